// Round 7
// baseline (6539.397 us; speedup 1.0000x reference)
//
#include <hip/hip_runtime.h>
#include <hip/hip_bf16.h>

// MultiTokenPrediction: main head logits + fused CE for main + 2 aux heads.
// B=1, S=2048, D=1024, V=50257, heads predict t+1 (main), t+2, t+3 (aux).

typedef __hip_bfloat16 bf16;
typedef __attribute__((ext_vector_type(8))) short bf16x8;
typedef __attribute__((ext_vector_type(4))) float f32x4;

typedef const __attribute__((address_space(1))) void* gptr_t;
typedef __attribute__((address_space(3))) void* lptr_t;

#define S_LEN   2048
#define DMODEL  1024
#define VOCAB   50257
#define VPAD2   51200   // 200*256 (8x8x25 block swizzle bijective)
#define NT256   200     // VPAD2/256

__device__ __forceinline__ void gload_lds16(const void* g, void* l) {
  __builtin_amdgcn_global_load_lds((gptr_t)g, (lptr_t)l, 16, 0, 0);
}

// ---------------- f32 -> bf16 conversion with row zero-padding ----------------
__global__ __launch_bounds__(256) void k_cvt(const float* __restrict__ src,
                                             bf16* __restrict__ dst,
                                             long rows_src, long rows_pad) {
  const long total4 = rows_pad << 8;
  for (long i = (long)blockIdx.x * 256 + threadIdx.x; i < total4;
       i += (long)gridDim.x * 256) {
    const long e = i << 2;
    const long row = e >> 10;
    alignas(8) bf16 o[4];
    if (row < rows_src) {
      const float4 v = *(const float4*)(src + e);
      o[0] = __float2bfloat16(v.x); o[1] = __float2bfloat16(v.y);
      o[2] = __float2bfloat16(v.z); o[3] = __float2bfloat16(v.w);
    } else {
      o[0] = o[1] = o[2] = o[3] = __float2bfloat16(0.f);
    }
    *(uint2*)(dst + e) = *(const uint2*)o;
  }
}

// ---------------- RMSNorm row kernel: f32 in, bf16 out ----------------
__global__ __launch_bounds__(256) void k_rms(const float* __restrict__ x,
                                             const float* __restrict__ w,
                                             bf16* __restrict__ xn) {
  const int row = blockIdx.x;
  const int t = threadIdx.x;
  const float4 v = ((const float4*)(x + (size_t)row * DMODEL))[t];
  float ss = v.x*v.x + v.y*v.y + v.z*v.z + v.w*v.w;
  #pragma unroll
  for (int d = 1; d < 64; d <<= 1) ss += __shfl_xor(ss, d, 64);
  __shared__ float red[4];
  if ((t & 63) == 0) red[t >> 6] = ss;
  __syncthreads();
  const float tot = red[0] + red[1] + red[2] + red[3];
  const float scale = rsqrtf(tot * (1.f / DMODEL) + 1e-5f);
  const float4 wv = ((const float4*)w)[t];
  alignas(8) bf16 o[4];
  o[0] = __float2bfloat16(v.x * scale * wv.x);
  o[1] = __float2bfloat16(v.y * scale * wv.y);
  o[2] = __float2bfloat16(v.z * scale * wv.z);
  o[3] = __float2bfloat16(v.w * scale * wv.w);
  *(uint2*)(xn + (size_t)row * DMODEL + t * 4) = *(const uint2*)o;
}

// ============ 256x256 bf16 MFMA GEMM, 2-slot dbuf + 2 blocks/CU, fused CE ============
// C[m][n] = sum_k A[m][k]*B[n][k]. grid(1600): bm=(id>>3)&7, bn=(id&7)+8*(id>>6)
// (8 bm-siblings share id%8 -> same XCD -> B L2-shared; FETCH 166MB verified R4).
// K split into 32 halves of 32 cols; 2 rotating 32KB LDS slots (A 16KB + B 16KB).
// Classic double-buffer: during half j stage half j+1 into slot j^1 (A in P0,
// B in P1), drain vmcnt(0) at end of half. The per-half drain stall is covered
// by the CO-RESIDENT SECOND BLOCK: LDS 74.75KB < 80KB and launch_bounds(512,4)
// give 2 blocks/CU (16 waves) -- the CU-TLP axis untested in R2-R5 (all 1/CU).
// Slot layout per array: 16 subtiles [16r][32c] (1KB), logical byte
// (r,c)=(r>>4)*1024+(r&15)*64+c*2, physical = logical^((logical>>9)&1)<<5
// (st_16x32). Swizzle both sides: read offset XORed, DMA source col
// pre-swizzled, DMA dest linear (rule #21; conflict-free verified R3).
template<bool WRITE_OUT>
__global__ __launch_bounds__(512, 4)
void k_gemm256(const bf16* __restrict__ A, const bf16* __restrict__ B,
               float* __restrict__ C, long ldc, int Nvalid,
               const int* __restrict__ targets, int shift,
               float* __restrict__ pmax, float* __restrict__ psum,
               float* __restrict__ ptgt, int ntiles) {
  __shared__ char lds[65536 + 9216];

  const int t = threadIdx.x;
  const int w = t >> 6, l = t & 63;
  const int g = l >> 4, q = l & 15;
  const int wr = w >> 2, wc = w & 3;
  const int id = blockIdx.x;
  const int bm = (id >> 3) & 7;
  const int bn = (id & 7) + ((id >> 6) << 3);

  f32x4 acc[8][4];
  #pragma unroll
  for (int i = 0; i < 8; ++i)
    #pragma unroll
    for (int j = 0; j < 4; ++j)
      #pragma unroll
      for (int r = 0; r < 4; ++r) acc[i][j][r] = 0.f;

  // staging source pointers (per-lane); half j at byte offset j*64 (immediate)
  const int srow = (l >> 2);
  const int scol = ((l & 3) * 8) ^ (((l >> 5) & 1) * 16);   // pre-swizzled col
  const char* gA0 = (const char*)(A + (size_t)(bm * 256 + w * 32 + srow) * DMODEL + scol);
  const char* gA1 = gA0 + (size_t)16 * DMODEL * 2;
  const char* gB0 = (const char*)(B + (size_t)(bn * 256 + w * 32 + srow) * DMODEL + scol);
  const char* gB1 = gB0 + (size_t)16 * DMODEL * 2;

  // frag-read bases (st_16x32-swizzled lane offset)
  const int laneoff = (q * 64 + g * 16) ^ (((q >> 3) & 1) << 5);
  const char* rdA = lds + wr * 8192 + laneoff;
  const char* rdB = lds + 16384 + wc * 4096 + laneoff;

  auto lda = [&](int s, int mi) {
    return *(const bf16x8*)(rdA + s * 32768 + mi * 1024);
  };
  auto ldb = [&](int s, int ni) {
    return *(const bf16x8*)(rdB + s * 32768 + ni * 1024);
  };
  auto stageA = [&](int s, int koff) {
    char* lb = lds + s * 32768 + w * 2048;
    gload_lds16(gA0 + koff, lb);
    gload_lds16(gA1 + koff, lb + 1024);
  };
  auto stageB = [&](int s, int koff) {
    char* lb = lds + s * 32768 + 16384 + w * 2048;
    gload_lds16(gB0 + koff, lb);
    gload_lds16(gB1 + koff, lb + 1024);
  };

  // ---- prologue: stage half 0 into slot 0; drain ----
  stageA(0, 0); stageB(0, 0);
  asm volatile("s_waitcnt vmcnt(0)" ::: "memory");
  __builtin_amdgcn_s_barrier();

  // ---- main loop: 32 K-halves, fully unrolled (all indices fold) ----
  #pragma unroll
  for (int j = 0; j < 32; ++j) {
    const int s = j & 1;
    const bool pre = j < 31;
    const int koff = (j + 1) * 64;
    bf16x8 a[4], b[4];

    // ---- P0: mi 0-3 ----
    #pragma unroll
    for (int mi = 0; mi < 4; ++mi) a[mi] = lda(s, mi);
    #pragma unroll
    for (int ni = 0; ni < 4; ++ni) b[ni] = ldb(s, ni);
    if (pre) stageA(s ^ 1, koff);
    __builtin_amdgcn_s_barrier();
    __builtin_amdgcn_s_setprio(1);
    #pragma unroll
    for (int mi = 0; mi < 4; ++mi)
      #pragma unroll
      for (int ni = 0; ni < 4; ++ni)
        acc[mi][ni] = __builtin_amdgcn_mfma_f32_16x16x32_bf16(a[mi], b[ni], acc[mi][ni], 0, 0, 0);
    __builtin_amdgcn_s_setprio(0);
    __builtin_amdgcn_s_barrier();

    // ---- P1: mi 4-7 ----
    #pragma unroll
    for (int mi = 0; mi < 4; ++mi) a[mi] = lda(s, 4 + mi);
    if (pre) stageB(s ^ 1, koff);
    __builtin_amdgcn_s_barrier();
    __builtin_amdgcn_s_setprio(1);
    #pragma unroll
    for (int mi = 0; mi < 4; ++mi)
      #pragma unroll
      for (int ni = 0; ni < 4; ++ni)
        acc[4 + mi][ni] = __builtin_amdgcn_mfma_f32_16x16x32_bf16(a[mi], b[ni], acc[4 + mi][ni], 0, 0, 0);
    __builtin_amdgcn_s_setprio(0);
    if (pre) asm volatile("s_waitcnt vmcnt(0)" ::: "memory");  // half j+1 landed
    __builtin_amdgcn_s_barrier();
  }

  // ---------------- epilogue: C write ----------------
  if constexpr (WRITE_OUT) {
    #pragma unroll
    for (int mi = 0; mi < 8; ++mi) {
      #pragma unroll
      for (int r = 0; r < 4; ++r) {
        const long row = bm * 256 + wr * 128 + mi * 16 + g * 4 + r;
        #pragma unroll
        for (int ni = 0; ni < 4; ++ni) {
          const int col = bn * 256 + wc * 64 + ni * 16 + q;
          if (col < Nvalid) C[row * ldc + col] = acc[mi][ni][r];
        }
      }
    }
  }

  // ---------------- fused CE partials ----------------
  {
    float* lds_m = (float*)(lds + 65536);   // [256][4]
    float* lds_s = lds_m + 1024;            // [256][4]
    int* lds_tgt = (int*)(lds_s + 1024);    // [256]
    if (t < 256) {
      const int rowg = bm * 256 + t;
      lds_tgt[t] = (rowg < S_LEN - shift) ? targets[rowg + shift] : -1;
    }
    __syncthreads();
    #pragma unroll
    for (int mi = 0; mi < 8; ++mi) {
      #pragma unroll
      for (int r = 0; r < 4; ++r) {
        const int rl = wr * 128 + mi * 16 + g * 4 + r;
        const int tgt = lds_tgt[rl];
        float v[4];
        #pragma unroll
        for (int ni = 0; ni < 4; ++ni) {
          const int n = bn * 256 + wc * 64 + ni * 16 + q;
          const float av = acc[mi][ni][r];
          if (n == tgt) ptgt[bm * 256 + rl] = av;
          v[ni] = (n < Nvalid) ? av : -1e30f;
        }
        float m = fmaxf(fmaxf(v[0], v[1]), fmaxf(v[2], v[3]));
        #pragma unroll
        for (int d = 1; d < 16; d <<= 1) m = fmaxf(m, __shfl_xor(m, d, 64));
        float s = 0.f;
        #pragma unroll
        for (int ni = 0; ni < 4; ++ni) s += __expf(v[ni] - m);
        #pragma unroll
        for (int d = 1; d < 16; d <<= 1) s += __shfl_xor(s, d, 64);
        if (q == 0) { lds_m[rl * 4 + wc] = m; lds_s[rl * 4 + wc] = s; }
      }
    }
    __syncthreads();
    if (t < 256) {
      float M = lds_m[t * 4 + 0], Ssum = lds_s[t * 4 + 0];
      #pragma unroll
      for (int c = 1; c < 4; ++c) {
        const float m2 = lds_m[t * 4 + c], s2 = lds_s[t * 4 + c];
        const float nM = fmaxf(M, m2);
        Ssum = Ssum * __expf(M - nM) + s2 * __expf(m2 - nM);
        M = nM;
      }
      const size_t idx = (size_t)(bm * 256 + t) * ntiles + bn;
      pmax[idx] = M;
      psum[idx] = Ssum;
    }
  }
}

// ---------------- 128x128 GEMM (small d->d projection) ----------------
__global__ __launch_bounds__(256, 2)
void k_gemm(const bf16* __restrict__ A, const bf16* __restrict__ B,
            float* __restrict__ C, long ldc, int Nvalid) {
  constexpr int K = DMODEL;
  __shared__ bf16 As[128 * 32];
  __shared__ bf16 Bs[128 * 32];

  const int t = threadIdx.x;
  const int bn = blockIdx.x, bm = blockIdx.y;
  const int w = t >> 6, l = t & 63, g = l >> 4, q = l & 15;
  const int wr = w >> 1, wc = w & 1;

  f32x4 acc[4][4];
  #pragma unroll
  for (int i = 0; i < 4; ++i)
    #pragma unroll
    for (int j = 0; j < 4; ++j)
      #pragma unroll
      for (int r = 0; r < 4; ++r) acc[i][j][r] = 0.f;

  char* lA0 = (char*)As + w * 1024;
  char* lA1 = (char*)As + 4096 + w * 1024;
  char* lB0 = (char*)Bs + w * 1024;
  char* lB1 = (char*)Bs + 4096 + w * 1024;
  const char* gA0 = (const char*)(A + (size_t)(bm * 128 + (t >> 2)) * K) + (t & 3) * 16;
  const char* gA1 = gA0 + (size_t)64 * K * 2;
  const char* gB0 = (const char*)(B + (size_t)(bn * 128 + (t >> 2)) * K) + (t & 3) * 16;
  const char* gB1 = gB0 + (size_t)64 * K * 2;

  for (int k0 = 0; k0 < K; k0 += 32) {
    const int kb = k0 * 2;
    gload_lds16(gA0 + kb, lA0);
    gload_lds16(gA1 + kb, lA1);
    gload_lds16(gB0 + kb, lB0);
    gload_lds16(gB1 + kb, lB1);
    __syncthreads();
    bf16x8 a[4], b[4];
    #pragma unroll
    for (int mi = 0; mi < 4; ++mi)
      a[mi] = *(const bf16x8*)&As[(wr * 64 + mi * 16 + q) * 32 + g * 8];
    #pragma unroll
    for (int ni = 0; ni < 4; ++ni)
      b[ni] = *(const bf16x8*)&Bs[(wc * 64 + ni * 16 + q) * 32 + g * 8];
    #pragma unroll
    for (int mi = 0; mi < 4; ++mi)
      #pragma unroll
      for (int ni = 0; ni < 4; ++ni)
        acc[mi][ni] = __builtin_amdgcn_mfma_f32_16x16x32_bf16(a[mi], b[ni], acc[mi][ni], 0, 0, 0);
    __syncthreads();
  }

  #pragma unroll
  for (int mi = 0; mi < 4; ++mi) {
    #pragma unroll
    for (int r = 0; r < 4; ++r) {
      const long row = bm * 128 + wr * 64 + mi * 16 + g * 4 + r;
      #pragma unroll
      for (int ni = 0; ni < 4; ++ni) {
        const int col = bn * 128 + wc * 64 + ni * 16 + q;
        if (col < Nvalid) C[row * ldc + col] = acc[mi][ni][r];
      }
    }
  }
}

// ---------------- combine per-row partials -> NLL ----------------
__global__ __launch_bounds__(64) void k_combine(const float* __restrict__ pmax,
                                                const float* __restrict__ psum,
                                                const float* __restrict__ ptgt,
                                                float* __restrict__ nll,
                                                int ntiles, int nv) {
  const int r = blockIdx.x;
  const int l = threadIdx.x;
  float M = -1e30f, Ssum = 0.f;
  for (int tl = l; tl < ntiles; tl += 64) {
    const float m = pmax[(size_t)r * ntiles + tl];
    const float s = psum[(size_t)r * ntiles + tl];
    const float nM = fmaxf(M, m);
    Ssum = Ssum * __expf(M - nM) + s * __expf(m - nM);
    M = nM;
  }
  #pragma unroll
  for (int d = 1; d < 64; d <<= 1) {
    const float m2 = __shfl_xor(M, d, 64);
    const float s2 = __shfl_xor(Ssum, d, 64);
    const float nM = fmaxf(M, m2);
    Ssum = Ssum * __expf(M - nM) + s2 * __expf(m2 - nM);
    M = nM;
  }
  if (l == 0) nll[r] = (r < nv) ? (M + logf(Ssum) - ptgt[r]) : 0.f;
}

// ---------------- final loss ----------------
__global__ __launch_bounds__(256) void k_loss(const float* __restrict__ nll,
                                              float* __restrict__ out) {
  __shared__ float sh[256];
  const int t = threadIdx.x;
  float sums[3];
  #pragma unroll
  for (int h = 0; h < 3; ++h) {
    const int nv = 2047 - h;
    float s = 0.f;
    for (int r = t; r < nv; r += 256) s += nll[h * 2048 + r];
    sh[t] = s; __syncthreads();
    for (int off = 128; off > 0; off >>= 1) {
      if (t < off) sh[t] += sh[t + off];
      __syncthreads();
    }
    sums[h] = sh[0]; __syncthreads();
  }
  if (t == 0)
    out[0] = sums[0] / 2047.f + 0.3f * 0.5f * (sums[1] / 2046.f + sums[2] / 2045.f);
}

extern "C" void kernel_launch(void* const* d_in, const int* in_sizes, int n_in,
                              void* d_out, int out_size, void* d_ws, size_t ws_size,
                              hipStream_t stream) {
  const float* hidden      = (const float*)d_in[0];
  const int*   targets     = (const int*)d_in[1];
  const float* emb_w       = (const float*)d_in[2];
  const float* main_norm_w = (const float*)d_in[3];
  const float* aux_proj_w  = (const float*)d_in[4];
  const float* aux_norm_w  = (const float*)d_in[5];
  const float* aux_out_w   = (const float*)d_in[6];
  float* out = (float*)d_out;

  char* ws = (char*)d_ws;
  bf16*  Wb    = (bf16*)(ws);                   // [VPAD2][1024] bf16
  bf16*  hb    = (bf16*)(ws + 104857600);       // hidden bf16
  bf16*  xn    = (bf16*)(ws + 109051904);       // normalized input bf16
  bf16*  projb = (bf16*)(ws + 113246208);       // aux proj weights bf16
  float* hbuf  = (float*)(ws + 117440512);      // aux pre-norm f32
  float* pmax  = (float*)(ws + 125829120);      // [2048][200]
  float* psum  = (float*)(ws + 127467520);      // [2048][200]
  float* ptgt  = (float*)(ws + 129105920);      // [2048]
  float* nll   = (float*)(ws + 129114112);      // [3][2048]

  // prep
  k_cvt<<<2048, 256, 0, stream>>>(hidden, hb, 2048, 2048);
  k_cvt<<<2048, 256, 0, stream>>>(aux_proj_w, projb, 2048, 2048);
  k_rms<<<2048, 256, 0, stream>>>(hidden, main_norm_w, xn);

  // ---- main head ----
  k_cvt<<<2048, 256, 0, stream>>>(emb_w, Wb, VOCAB, VPAD2);
  k_gemm256<true><<<1600, 512, 0, stream>>>(
      xn, Wb, out, VOCAB, VOCAB, targets, 1, pmax, psum, ptgt, NT256);
  k_combine<<<2048, 64, 0, stream>>>(pmax, psum, ptgt, nll, NT256, 2047);

  // ---- aux heads ----
  for (int i = 0; i < 2; ++i) {
    k_cvt<<<2048, 256, 0, stream>>>(aux_out_w + (size_t)i * VOCAB * DMODEL, Wb, VOCAB, VPAD2);
    k_gemm<<<dim3(8, 16), 256, 0, stream>>>(
        hb, projb + (size_t)i * DMODEL * DMODEL, hbuf, DMODEL, DMODEL);
    k_rms<<<2048, 256, 0, stream>>>(hbuf, aux_norm_w + (size_t)i * DMODEL, xn);
    k_gemm256<false><<<1600, 512, 0, stream>>>(
        xn, Wb, nullptr, 0, VOCAB, targets, i + 2, pmax, psum, ptgt, NT256);
    k_combine<<<2048, 64, 0, stream>>>(pmax, psum, ptgt, nll + (i + 1) * 2048, NT256, 2048 - (i + 2));
  }

  k_loss<<<1, 256, 0, stream>>>(nll, out + (size_t)S_LEN * VOCAB);
}

// Round 8
// 1287.929 us; speedup vs baseline: 5.0775x; 5.0775x over previous
//
#include <hip/hip_runtime.h>
#include <hip/hip_bf16.h>

// MultiTokenPrediction: main head logits + fused CE for main + 2 aux heads.
// B=1, S=2048, D=1024, V=50257, heads predict t+1 (main), t+2, t+3 (aux).

typedef __hip_bfloat16 bf16;
typedef __attribute__((ext_vector_type(8))) short bf16x8;
typedef __attribute__((ext_vector_type(4))) float f32x4;

typedef const __attribute__((address_space(1))) void* gptr_t;
typedef __attribute__((address_space(3))) void* lptr_t;

#define S_LEN   2048
#define DMODEL  1024
#define VOCAB   50257
#define NT256   200     // 200*256 = 51200 padded N (8x8x25 block swizzle bijective)

__device__ __forceinline__ void gload_lds16(const void* g, void* l) {
  __builtin_amdgcn_global_load_lds((gptr_t)g, (lptr_t)l, 16, 0, 0);
}

// ---------------- f32 -> bf16 conversion (small buffers only) ----------------
__global__ __launch_bounds__(256) void k_cvt(const float* __restrict__ src,
                                             bf16* __restrict__ dst,
                                             long rows_src, long rows_pad) {
  const long total4 = rows_pad << 8;
  for (long i = (long)blockIdx.x * 256 + threadIdx.x; i < total4;
       i += (long)gridDim.x * 256) {
    const long e = i << 2;
    const long row = e >> 10;
    alignas(8) bf16 o[4];
    if (row < rows_src) {
      const float4 v = *(const float4*)(src + e);
      o[0] = __float2bfloat16(v.x); o[1] = __float2bfloat16(v.y);
      o[2] = __float2bfloat16(v.z); o[3] = __float2bfloat16(v.w);
    } else {
      o[0] = o[1] = o[2] = o[3] = __float2bfloat16(0.f);
    }
    *(uint2*)(dst + e) = *(const uint2*)o;
  }
}

// ---------------- RMSNorm row kernel: f32 in, bf16 out ----------------
__global__ __launch_bounds__(256) void k_rms(const float* __restrict__ x,
                                             const float* __restrict__ w,
                                             bf16* __restrict__ xn) {
  const int row = blockIdx.x;
  const int t = threadIdx.x;
  const float4 v = ((const float4*)(x + (size_t)row * DMODEL))[t];
  float ss = v.x*v.x + v.y*v.y + v.z*v.z + v.w*v.w;
  #pragma unroll
  for (int d = 1; d < 64; d <<= 1) ss += __shfl_xor(ss, d, 64);
  __shared__ float red[4];
  if ((t & 63) == 0) red[t >> 6] = ss;
  __syncthreads();
  const float tot = red[0] + red[1] + red[2] + red[3];
  const float scale = rsqrtf(tot * (1.f / DMODEL) + 1e-5f);
  const float4 wv = ((const float4*)w)[t];
  alignas(8) bf16 o[4];
  o[0] = __float2bfloat16(v.x * scale * wv.x);
  o[1] = __float2bfloat16(v.y * scale * wv.y);
  o[2] = __float2bfloat16(v.z * scale * wv.z);
  o[3] = __float2bfloat16(v.w * scale * wv.w);
  *(uint2*)(xn + (size_t)row * DMODEL + t * 4) = *(const uint2*)o;
}

// ============ 256x256 MFMA GEMM: A bf16 LDS, B *f32* LDS (cvt on read) ============
// C[m][n] = sum_k A[m][k]*Bf[n][k]. Bf is the RAW f32 weight matrix -- no
// separate bf16 conversion pass (saves 3x ~50us serial cvt dispatches).
// grid(1600): bm=(id>>3)&7, bn=(id&7)+8*(id>>6) (8 bm-siblings -> same XCD).
// K split into 32 halves of 32 cols; SLOTS=3 rotating 48KB LDS slots
// (A bf16 16KB + B f32 32KB). During half j stage half j+2 into slot (j+2)%3;
// end-of-half vmcnt(6) drains half j+1 (half j+2's 6 loads stay in flight).
// A layout/swizzle: R4-identical (verified conflict-free R3).
// B f32 layout: 16 subtiles [16r][32 f32] (2KB), logical byte (r,c)=r*128+c*4,
// physical = logical ^ ((r&7)<<4). Read: lane(q,g) 2x ds_read_b128 at
// (q*128+g*32{+16}) ^ ((q&7)<<4) -> banks evenly loaded (8 lanes/4-bank group).
// DMA: dest linear, source f32-col pre-swizzled 4*((l&7)^(l>>3)) (rule #21).
// OOB rows (>=VOCAB) clamped to VOCAB-1; those cols masked in CE/C-write.
template<bool WRITE_OUT>
__global__ __launch_bounds__(512, 2)
void k_gemm256(const bf16* __restrict__ A, const float* __restrict__ Bf,
               float* __restrict__ C, long ldc, int Nvalid,
               const int* __restrict__ targets, int shift,
               float* __restrict__ pmax, float* __restrict__ psum,
               float* __restrict__ ptgt, int ntiles) {
  constexpr int SLOT = 49152;
  __shared__ char lds[3 * SLOT + 9216];

  const int t = threadIdx.x;
  const int w = t >> 6, l = t & 63;
  const int g = l >> 4, q = l & 15;
  const int wr = w >> 2, wc = w & 3;
  const int id = blockIdx.x;
  const int bm = (id >> 3) & 7;
  const int bn = (id & 7) + ((id >> 6) << 3);

  f32x4 acc[8][4];
  #pragma unroll
  for (int i = 0; i < 8; ++i)
    #pragma unroll
    for (int j = 0; j < 4; ++j)
      #pragma unroll
      for (int r = 0; r < 4; ++r) acc[i][j][r] = 0.f;

  // ---- A staging source (bf16; R4-identical) ----
  const int srow = (l >> 2);
  const int scolA = ((l & 3) * 8) ^ (((l >> 5) & 1) * 16);
  const char* gA0 = (const char*)(A + (size_t)(bm * 256 + w * 32 + srow) * DMODEL + scolA);
  const char* gA1 = gA0 + (size_t)16 * DMODEL * 2;

  // ---- B staging source (f32, per-lane, row-clamped, col pre-swizzled) ----
  const int bcolf = 4 * ((l & 7) ^ (l >> 3));   // f32 col within the 32-col half
  const char* gB[4];
  #pragma unroll
  for (int jj = 0; jj < 4; ++jj) {
    int row = bn * 256 + w * 32 + (jj >> 1) * 16 + (jj & 1) * 8 + (l >> 3);
    if (row > VOCAB - 1) row = VOCAB - 1;
    gB[jj] = (const char*)(Bf + (size_t)row * DMODEL + bcolf);
  }

  // ---- frag-read bases ----
  const int laneoffA = (q * 64 + g * 16) ^ (((q >> 3) & 1) << 5);
  const char* rdA = lds + wr * 8192 + laneoffA;
  const int boff0 = (q * 128 + g * 32) ^ ((q & 7) << 4);
  const int boff1 = (q * 128 + g * 32 + 16) ^ ((q & 7) << 4);
  const char* rdB0 = lds + 16384 + wc * 8192 + boff0;
  const char* rdB1 = lds + 16384 + wc * 8192 + boff1;

  auto lda = [&](int s, int mi) {
    return *(const bf16x8*)(rdA + s * SLOT + mi * 1024);
  };
  auto ldb = [&](int s, int ni) {
    f32x4 lo = *(const f32x4*)(rdB0 + s * SLOT + ni * 2048);
    f32x4 hi = *(const f32x4*)(rdB1 + s * SLOT + ni * 2048);
    alignas(16) bf16 tmp[8];
    tmp[0] = __float2bfloat16(lo[0]); tmp[1] = __float2bfloat16(lo[1]);
    tmp[2] = __float2bfloat16(lo[2]); tmp[3] = __float2bfloat16(lo[3]);
    tmp[4] = __float2bfloat16(hi[0]); tmp[5] = __float2bfloat16(hi[1]);
    tmp[6] = __float2bfloat16(hi[2]); tmp[7] = __float2bfloat16(hi[3]);
    return *(const bf16x8*)tmp;
  };
  auto stageA = [&](int s, int koff) {      // koff = half*64 bytes
    char* lb = lds + s * SLOT + w * 2048;
    gload_lds16(gA0 + koff, lb);
    gload_lds16(gA1 + koff, lb + 1024);
  };
  auto stageB = [&](int s, int koff) {      // koff = half*128 bytes (f32)
    char* lb = lds + s * SLOT + 16384 + w * 4096;
    gload_lds16(gB[0] + koff, lb);
    gload_lds16(gB[1] + koff, lb + 1024);
    gload_lds16(gB[2] + koff, lb + 2048);
    gload_lds16(gB[3] + koff, lb + 3072);
  };

  // ---- prologue: stage halves 0,1; drain half 0 (6 of 12 loads) ----
  stageA(0, 0);   stageB(0, 0);
  stageA(1, 64);  stageB(1, 128);
  asm volatile("s_waitcnt vmcnt(6)" ::: "memory");
  __builtin_amdgcn_s_barrier();

  // ---- main loop: 32 K-halves, fully unrolled ----
  #pragma unroll
  for (int j = 0; j < 32; ++j) {
    const int s = j % 3;
    const int sn = (j + 2) % 3;
    const bool pre = j <= 29;
    bf16x8 a[4], b[4];

    // ---- P0: mi 0-3 ----
    #pragma unroll
    for (int mi = 0; mi < 4; ++mi) a[mi] = lda(s, mi);
    #pragma unroll
    for (int ni = 0; ni < 4; ++ni) b[ni] = ldb(s, ni);
    if (pre) stageA(sn, (j + 2) * 64);
    __builtin_amdgcn_s_barrier();
    __builtin_amdgcn_s_setprio(1);
    #pragma unroll
    for (int mi = 0; mi < 4; ++mi)
      #pragma unroll
      for (int ni = 0; ni < 4; ++ni)
        acc[mi][ni] = __builtin_amdgcn_mfma_f32_16x16x32_bf16(a[mi], b[ni], acc[mi][ni], 0, 0, 0);
    __builtin_amdgcn_s_setprio(0);
    __builtin_amdgcn_s_barrier();

    // ---- P1: mi 4-7 ----
    #pragma unroll
    for (int mi = 0; mi < 4; ++mi) a[mi] = lda(s, 4 + mi);
    if (pre) stageB(sn, (j + 2) * 128);
    __builtin_amdgcn_s_barrier();
    __builtin_amdgcn_s_setprio(1);
    #pragma unroll
    for (int mi = 0; mi < 4; ++mi)
      #pragma unroll
      for (int ni = 0; ni < 4; ++ni)
        acc[4 + mi][ni] = __builtin_amdgcn_mfma_f32_16x16x32_bf16(a[mi], b[ni], acc[4 + mi][ni], 0, 0, 0);
    __builtin_amdgcn_s_setprio(0);
    if (j <= 29)      { asm volatile("s_waitcnt vmcnt(6)" ::: "memory"); }
    else if (j == 30) { asm volatile("s_waitcnt vmcnt(0)" ::: "memory"); }
    __builtin_amdgcn_s_barrier();
  }

  // ---------------- epilogue: C write ----------------
  if constexpr (WRITE_OUT) {
    #pragma unroll
    for (int mi = 0; mi < 8; ++mi) {
      #pragma unroll
      for (int r = 0; r < 4; ++r) {
        const long row = bm * 256 + wr * 128 + mi * 16 + g * 4 + r;
        #pragma unroll
        for (int ni = 0; ni < 4; ++ni) {
          const int col = bn * 256 + wc * 64 + ni * 16 + q;
          if (col < Nvalid) C[row * ldc + col] = acc[mi][ni][r];
        }
      }
    }
  }

  // ---------------- fused CE partials ----------------
  {
    float* lds_m = (float*)(lds + 3 * SLOT);   // [256][4]
    float* lds_s = lds_m + 1024;               // [256][4]
    int* lds_tgt = (int*)(lds_s + 1024);       // [256]
    if (t < 256) {
      const int rowg = bm * 256 + t;
      lds_tgt[t] = (rowg < S_LEN - shift) ? targets[rowg + shift] : -1;
    }
    __syncthreads();
    #pragma unroll
    for (int mi = 0; mi < 8; ++mi) {
      #pragma unroll
      for (int r = 0; r < 4; ++r) {
        const int rl = wr * 128 + mi * 16 + g * 4 + r;
        const int tgt = lds_tgt[rl];
        float v[4];
        #pragma unroll
        for (int ni = 0; ni < 4; ++ni) {
          const int n = bn * 256 + wc * 64 + ni * 16 + q;
          const float av = acc[mi][ni][r];
          if (n == tgt) ptgt[bm * 256 + rl] = av;
          v[ni] = (n < Nvalid) ? av : -1e30f;
        }
        float m = fmaxf(fmaxf(v[0], v[1]), fmaxf(v[2], v[3]));
        #pragma unroll
        for (int d = 1; d < 16; d <<= 1) m = fmaxf(m, __shfl_xor(m, d, 64));
        float s = 0.f;
        #pragma unroll
        for (int ni = 0; ni < 4; ++ni) s += __expf(v[ni] - m);
        #pragma unroll
        for (int d = 1; d < 16; d <<= 1) s += __shfl_xor(s, d, 64);
        if (q == 0) { lds_m[rl * 4 + wc] = m; lds_s[rl * 4 + wc] = s; }
      }
    }
    __syncthreads();
    if (t < 256) {
      float M = lds_m[t * 4 + 0], Ssum = lds_s[t * 4 + 0];
      #pragma unroll
      for (int c = 1; c < 4; ++c) {
        const float m2 = lds_m[t * 4 + c], s2 = lds_s[t * 4 + c];
        const float nM = fmaxf(M, m2);
        Ssum = Ssum * __expf(M - nM) + s2 * __expf(m2 - nM);
        M = nM;
      }
      const size_t idx = (size_t)(bm * 256 + t) * ntiles + bn;
      pmax[idx] = M;
      psum[idx] = Ssum;
    }
  }
}

// ---------------- 128x128 GEMM (small d->d projection) ----------------
__global__ __launch_bounds__(256, 2)
void k_gemm(const bf16* __restrict__ A, const bf16* __restrict__ B,
            float* __restrict__ C, long ldc, int Nvalid) {
  constexpr int K = DMODEL;
  __shared__ bf16 As[128 * 32];
  __shared__ bf16 Bs[128 * 32];

  const int t = threadIdx.x;
  const int bn = blockIdx.x, bm = blockIdx.y;
  const int w = t >> 6, l = t & 63, g = l >> 4, q = l & 15;
  const int wr = w >> 1, wc = w & 1;

  f32x4 acc[4][4];
  #pragma unroll
  for (int i = 0; i < 4; ++i)
    #pragma unroll
    for (int j = 0; j < 4; ++j)
      #pragma unroll
      for (int r = 0; r < 4; ++r) acc[i][j][r] = 0.f;

  char* lA0 = (char*)As + w * 1024;
  char* lA1 = (char*)As + 4096 + w * 1024;
  char* lB0 = (char*)Bs + w * 1024;
  char* lB1 = (char*)Bs + 4096 + w * 1024;
  const char* gA0 = (const char*)(A + (size_t)(bm * 128 + (t >> 2)) * K) + (t & 3) * 16;
  const char* gA1 = gA0 + (size_t)64 * K * 2;
  const char* gB0 = (const char*)(B + (size_t)(bn * 128 + (t >> 2)) * K) + (t & 3) * 16;
  const char* gB1 = gB0 + (size_t)64 * K * 2;

  for (int k0 = 0; k0 < K; k0 += 32) {
    const int kb = k0 * 2;
    gload_lds16(gA0 + kb, lA0);
    gload_lds16(gA1 + kb, lA1);
    gload_lds16(gB0 + kb, lB0);
    gload_lds16(gB1 + kb, lB1);
    __syncthreads();
    bf16x8 a[4], b[4];
    #pragma unroll
    for (int mi = 0; mi < 4; ++mi)
      a[mi] = *(const bf16x8*)&As[(wr * 64 + mi * 16 + q) * 32 + g * 8];
    #pragma unroll
    for (int ni = 0; ni < 4; ++ni)
      b[ni] = *(const bf16x8*)&Bs[(wc * 64 + ni * 16 + q) * 32 + g * 8];
    #pragma unroll
    for (int mi = 0; mi < 4; ++mi)
      #pragma unroll
      for (int ni = 0; ni < 4; ++ni)
        acc[mi][ni] = __builtin_amdgcn_mfma_f32_16x16x32_bf16(a[mi], b[ni], acc[mi][ni], 0, 0, 0);
    __syncthreads();
  }

  #pragma unroll
  for (int mi = 0; mi < 4; ++mi) {
    #pragma unroll
    for (int r = 0; r < 4; ++r) {
      const long row = bm * 128 + wr * 64 + mi * 16 + g * 4 + r;
      #pragma unroll
      for (int ni = 0; ni < 4; ++ni) {
        const int col = bn * 128 + wc * 64 + ni * 16 + q;
        if (col < Nvalid) C[row * ldc + col] = acc[mi][ni][r];
      }
    }
  }
}

// ---------------- combine per-row partials -> NLL ----------------
__global__ __launch_bounds__(64) void k_combine(const float* __restrict__ pmax,
                                                const float* __restrict__ psum,
                                                const float* __restrict__ ptgt,
                                                float* __restrict__ nll,
                                                int ntiles, int nv) {
  const int r = blockIdx.x;
  const int l = threadIdx.x;
  float M = -1e30f, Ssum = 0.f;
  for (int tl = l; tl < ntiles; tl += 64) {
    const float m = pmax[(size_t)r * ntiles + tl];
    const float s = psum[(size_t)r * ntiles + tl];
    const float nM = fmaxf(M, m);
    Ssum = Ssum * __expf(M - nM) + s * __expf(m - nM);
    M = nM;
  }
  #pragma unroll
  for (int d = 1; d < 64; d <<= 1) {
    const float m2 = __shfl_xor(M, d, 64);
    const float s2 = __shfl_xor(Ssum, d, 64);
    const float nM = fmaxf(M, m2);
    Ssum = Ssum * __expf(M - nM) + s2 * __expf(m2 - nM);
    M = nM;
  }
  if (l == 0) nll[r] = (r < nv) ? (M + logf(Ssum) - ptgt[r]) : 0.f;
}

// ---------------- final loss ----------------
__global__ __launch_bounds__(256) void k_loss(const float* __restrict__ nll,
                                              float* __restrict__ out) {
  __shared__ float sh[256];
  const int t = threadIdx.x;
  float sums[3];
  #pragma unroll
  for (int h = 0; h < 3; ++h) {
    const int nv = 2047 - h;
    float s = 0.f;
    for (int r = t; r < nv; r += 256) s += nll[h * 2048 + r];
    sh[t] = s; __syncthreads();
    for (int off = 128; off > 0; off >>= 1) {
      if (t < off) sh[t] += sh[t + off];
      __syncthreads();
    }
    sums[h] = sh[0]; __syncthreads();
  }
  if (t == 0)
    out[0] = sums[0] / 2047.f + 0.3f * 0.5f * (sums[1] / 2046.f + sums[2] / 2045.f);
}

extern "C" void kernel_launch(void* const* d_in, const int* in_sizes, int n_in,
                              void* d_out, int out_size, void* d_ws, size_t ws_size,
                              hipStream_t stream) {
  const float* hidden      = (const float*)d_in[0];
  const int*   targets     = (const int*)d_in[1];
  const float* emb_w       = (const float*)d_in[2];
  const float* main_norm_w = (const float*)d_in[3];
  const float* aux_proj_w  = (const float*)d_in[4];
  const float* aux_norm_w  = (const float*)d_in[5];
  const float* aux_out_w   = (const float*)d_in[6];
  float* out = (float*)d_out;

  char* ws = (char*)d_ws;
  bf16*  hb    = (bf16*)(ws);                   // hidden bf16, 4 MiB
  bf16*  xn    = (bf16*)(ws + 4194304);         // normalized input bf16, 4 MiB
  bf16*  projb = (bf16*)(ws + 8388608);         // aux proj weights bf16, 4 MiB
  float* hbuf  = (float*)(ws + 12582912);       // aux pre-norm f32, 8 MiB
  float* pmax  = (float*)(ws + 20971520);       // [2048][200]
  float* psum  = (float*)(ws + 22609920);       // [2048][200]
  float* ptgt  = (float*)(ws + 24248320);       // [2048]
  float* nll   = (float*)(ws + 24256512);       // [3][2048]

  // prep (small buffers only; big W matrices are read as f32 by the GEMM)
  k_cvt<<<2048, 256, 0, stream>>>(hidden, hb, 2048, 2048);
  k_cvt<<<2048, 256, 0, stream>>>(aux_proj_w, projb, 2048, 2048);
  k_rms<<<2048, 256, 0, stream>>>(hidden, main_norm_w, xn);

  // ---- main head ----
  k_gemm256<true><<<1600, 512, 0, stream>>>(
      xn, emb_w, out, VOCAB, VOCAB, targets, 1, pmax, psum, ptgt, NT256);
  k_combine<<<2048, 64, 0, stream>>>(pmax, psum, ptgt, nll, NT256, 2047);

  // ---- aux heads ----
  for (int i = 0; i < 2; ++i) {
    k_gemm<<<dim3(8, 16), 256, 0, stream>>>(
        hb, projb + (size_t)i * DMODEL * DMODEL, hbuf, DMODEL, DMODEL);
    k_rms<<<2048, 256, 0, stream>>>(hbuf, aux_norm_w + (size_t)i * DMODEL, xn);
    k_gemm256<false><<<1600, 512, 0, stream>>>(
        xn, aux_out_w + (size_t)i * VOCAB * DMODEL, nullptr, 0, VOCAB,
        targets, i + 2, pmax, psum, ptgt, NT256);
    k_combine<<<2048, 64, 0, stream>>>(pmax, psum, ptgt, nll + (i + 1) * 2048, NT256, 2048 - (i + 2));
  }

  k_loss<<<1, 256, 0, stream>>>(nll, out + (size_t)S_LEN * VOCAB);
}